// Round 4
// baseline (862.643 us; speedup 1.0000x reference)
//
#include <hip/hip_runtime.h>
#include <stdint.h>

// Problem constants
#define NROWS 1000000
#define DDIM  128
#define NCLS  1000

// (segment, class) counting sort: 32 segments x 31250 rows (16 MB each).
#define NSEG  32
#define SEGSZ 31250
#define NBUCK (NSEG * NCLS)          // 32000 buckets

// gather: dynamic 128-entry chunks pulled off a global counter.
#define CHUNK   128
#define TOTPAD  1048576              // padded entry count (sentinel tail)
#define NCHUNK  (TOTPAD / CHUNK)     // 8192
#define GBLOCKS 512

typedef float f4 __attribute__((ext_vector_type(4)));

// ws layout (4-byte words):
#define WS_SUMS    0          // 131072 floats (1024 rows x 128, sentinel rows incl.)
#define WS_HIST    131072     // 32000 ints   (seg*1000 + cls)
#define WS_CURSOR  163072     // 32000 ints   (bucket bases / cursors)
#define WS_COUNTS  195072     // 1000 ints    (per-class totals)
#define WS_VARD    196096     // 128 floats
#define WS_CTR     196224     // 1 int        (dynamic chunk counter)
#define WS_ENTRIES 196608     // 1048576 u32  (row | cls<<20)

__global__ __launch_bounds__(256) void zero_kernel(float* __restrict__ sums,
                                                   int* __restrict__ hist,
                                                   int* __restrict__ ctr) {
    int t = blockIdx.x * 256 + threadIdx.x;   // 128 blocks -> 32768 threads
    f4 z = {0.0f, 0.0f, 0.0f, 0.0f};
    ((f4*)sums)[t] = z;                        // 32768 f4 = 131072 floats
    if (t < NBUCK) hist[t] = 0;
    if (t == 0) *ctr = 0;
}

// 256 blocks: 8 per segment. LDS histogram of this slice's labels, merged into
// global hist[seg*1000+cls].
__global__ __launch_bounds__(256) void hist_kernel(const int* __restrict__ labels,
                                                   int* __restrict__ hist) {
    __shared__ int h[NCLS];
    const int sid = blockIdx.x >> 3;
    const int sl  = blockIdx.x & 7;
    const int sb  = sid * SEGSZ;
    const int lo  = sb + (SEGSZ * sl) / 8;
    const int hi  = sb + (SEGSZ * (sl + 1)) / 8;
    for (int e = threadIdx.x; e < NCLS; e += 256) h[e] = 0;
    __syncthreads();
    for (int r = lo + threadIdx.x; r < hi; r += 256)
        atomicAdd(&h[labels[r]], 1);
    __syncthreads();
    for (int e = threadIdx.x; e < NCLS; e += 256)
        if (h[e]) atomicAdd(&hist[sid * NCLS + e], h[e]);
}

// Single block: exclusive prefix over 32000 buckets -> cursor bases; per-class
// totals for the mean; sentinel tail of entries.
__global__ __launch_bounds__(1024) void scan_kernel(const int* __restrict__ hist,
                                                    int* __restrict__ cursor,
                                                    int* __restrict__ counts,
                                                    unsigned* __restrict__ entries) {
    __shared__ int part[1024];
    const int t  = threadIdx.x;
    const int lo = (NBUCK * t) >> 10;
    const int hi = (NBUCK * (t + 1)) >> 10;
    int s = 0;
    for (int i = lo; i < hi; ++i) s += hist[i];
    part[t] = s;
    __syncthreads();
    for (int off = 1; off < 1024; off <<= 1) {
        int v = 0;
        if (t >= off) v = part[t - off];
        __syncthreads();
        if (t >= off) part[t] += v;
        __syncthreads();
    }
    int run = part[t] - s;            // exclusive base for bucket range [lo,hi)
    for (int i = lo; i < hi; ++i) { cursor[i] = run; run += hist[i]; }
    // per-class totals
    for (int c = t; c < NCLS; c += 1024) {
        int cc = 0;
        for (int sg = 0; sg < NSEG; ++sg) cc += hist[sg * NCLS + c];
        counts[c] = cc;
    }
    // sentinel tail (class 1023, row 0; never flushed)
    for (int i = NROWS + t; i < TOTPAD; i += 1024)
        entries[i] = (1023u << 20);
}

// Counting-sort scatter: entries grouped by (segment, class), packed row|cls<<20.
__global__ __launch_bounds__(256) void scatter_kernel(const int* __restrict__ labels,
                                                      int* __restrict__ cursor,
                                                      unsigned* __restrict__ entries) {
    for (int r = blockIdx.x * 256 + threadIdx.x; r < NROWS; r += 1024 * 256) {
        int lbl = labels[r];
        int bkt = (r / SEGSZ) * NCLS + lbl;
        int pos = atomicAdd(&cursor[bkt], 1);
        entries[pos] = (unsigned)r | ((unsigned)lbl << 20);
    }
}

// Gather with dynamic chunk scheduling: waves pull consecutive 128-entry chunks
// off a global counter, so concurrently-in-flight reads cover a dense ~16-32 MB
// window (DRAM page locality), while (seg,class) runs (~31 entries) keep the
// accumulation in registers with rare atomic flushes. Correct for ANY order.
__global__ __launch_bounds__(512, 4) void gather_kernel(const float* __restrict__ emb,
                                                        const unsigned* __restrict__ entries,
                                                        int* __restrict__ ctr,
                                                        float* __restrict__ sums) {
    const f4* emb4 = (const f4*)emb;
    const int lane = threadIdx.x & 63;
    const int h    = lane >> 5;      // which entry of the pair
    const int q    = lane & 31;      // dims q*4 .. q*4+3

    f4 acc = {0.0f, 0.0f, 0.0f, 0.0f};
    unsigned cur = 0xFFFFFFFFu;

    for (;;) {
        int ch = 0;
        if (lane == 0) ch = atomicAdd(ctr, 1);
        ch = __shfl(ch, 0);
        if (ch >= NCHUNK) break;
        const int cb = ch * CHUNK;
        for (int b = 0; b < CHUNK / 64; ++b) {
            unsigned pk = entries[cb + b * 64 + lane];   // 64 entries in regs
            #pragma unroll
            for (int g = 0; g < 4; ++g) {
                unsigned pks[8];
                f4 vv[8];
                #pragma unroll
                for (int u = 0; u < 8; ++u) {
                    pks[u] = __shfl((int)pk, g * 16 + 2 * u + h);
                    vv[u]  = __builtin_nontemporal_load(
                                 &emb4[(size_t)(pks[u] & 0xFFFFFu) * 32 + q]);
                }
                #pragma unroll
                for (int u = 0; u < 8; ++u) {
                    unsigned c = pks[u] >> 20;
                    if (c != cur) {                 // run boundary (rare)
                        if (cur < NCLS) {
                            unsafeAtomicAdd(&sums[cur * DDIM + q * 4 + 0], acc.x);
                            unsafeAtomicAdd(&sums[cur * DDIM + q * 4 + 1], acc.y);
                            unsafeAtomicAdd(&sums[cur * DDIM + q * 4 + 2], acc.z);
                            unsafeAtomicAdd(&sums[cur * DDIM + q * 4 + 3], acc.w);
                        }
                        f4 z = {0.0f, 0.0f, 0.0f, 0.0f};
                        acc = z;
                        cur = c;
                    }
                    acc += vv[u];
                }
            }
        }
    }
    if (cur < NCLS) {
        unsafeAtomicAdd(&sums[cur * DDIM + q * 4 + 0], acc.x);
        unsafeAtomicAdd(&sums[cur * DDIM + q * 4 + 1], acc.y);
        unsafeAtomicAdd(&sums[cur * DDIM + q * 4 + 2], acc.z);
        unsafeAtomicAdd(&sums[cur * DDIM + q * 4 + 3], acc.w);
    }
}

// One block per dim d: variance over 1000 class means (ddof=1) -> var_d[d].
__global__ __launch_bounds__(256) void var_kernel(const float* __restrict__ sums,
                                                  const int* __restrict__ counts,
                                                  float* __restrict__ var_d) {
    const int d = blockIdx.x;
    float s1 = 0.0f, s2 = 0.0f;
    for (int c = threadIdx.x; c < NCLS; c += 256) {
        float mv = sums[c * DDIM + d] / (float)counts[c];
        s1 += mv;
        s2 += mv * mv;
    }
    #pragma unroll
    for (int off = 32; off; off >>= 1) {
        s1 += __shfl_down(s1, off);
        s2 += __shfl_down(s2, off);
    }
    __shared__ float p1[4], p2[4];
    int wave = threadIdx.x >> 6, lane = threadIdx.x & 63;
    if (lane == 0) { p1[wave] = s1; p2[wave] = s2; }
    __syncthreads();
    if (threadIdx.x == 0) {
        float t1 = p1[0] + p1[1] + p1[2] + p1[3];
        float t2 = p2[0] + p2[1] + p2[2] + p2[3];
        var_d[d] = (t2 - t1 * t1 / (float)NCLS) / (float)(NCLS - 1);
    }
}

__global__ __launch_bounds__(64) void final_kernel(const float* __restrict__ var_d,
                                                   float* __restrict__ out) {
    float s = var_d[threadIdx.x] + var_d[threadIdx.x + 64];
    #pragma unroll
    for (int off = 32; off; off >>= 1) s += __shfl_down(s, off);
    if (threadIdx.x == 0) out[0] = -s / (float)DDIM;
}

extern "C" void kernel_launch(void* const* d_in, const int* in_sizes, int n_in,
                              void* d_out, int out_size, void* d_ws, size_t ws_size,
                              hipStream_t stream) {
    const float* emb    = (const float*)d_in[0];
    const int*   labels = (const int*)d_in[1];
    float*    wsf     = (float*)d_ws;
    int*      wsi     = (int*)d_ws;
    float*    sums    = wsf + WS_SUMS;
    int*      hist    = wsi + WS_HIST;
    int*      cursor  = wsi + WS_CURSOR;
    int*      counts  = wsi + WS_COUNTS;
    float*    var_d   = wsf + WS_VARD;
    int*      ctr     = wsi + WS_CTR;
    unsigned* entries = (unsigned*)d_ws + WS_ENTRIES;
    float*    out     = (float*)d_out;

    hipLaunchKernelGGL(zero_kernel, dim3(128), dim3(256), 0, stream, sums, hist, ctr);
    hipLaunchKernelGGL(hist_kernel, dim3(256), dim3(256), 0, stream, labels, hist);
    hipLaunchKernelGGL(scan_kernel, dim3(1), dim3(1024), 0, stream, hist, cursor, counts, entries);
    hipLaunchKernelGGL(scatter_kernel, dim3(1024), dim3(256), 0, stream, labels, cursor, entries);
    hipLaunchKernelGGL(gather_kernel, dim3(GBLOCKS), dim3(512), 0, stream, emb, entries, ctr, sums);
    hipLaunchKernelGGL(var_kernel, dim3(DDIM), dim3(256), 0, stream, sums, counts, var_d);
    hipLaunchKernelGGL(final_kernel, dim3(1), dim3(64), 0, stream, var_d, out);
}